// Round 2
// baseline (159.018 us; speedup 1.0000x reference)
//
#include <hip/hip_runtime.h>
#include <hip/hip_cooperative_groups.h>

namespace cg = cooperative_groups;

#define R 128
#define C 80
#define HH 28
#define WW 28
#define NPIX 784          // 28*28
#define BIGD (1 << 26)    // sentinel for "no opposite pixel in this row"

// Single cooperative kernel, two phases separated by grid.sync().
//
// Phase A (256 blocks, one per (image, field)): blocks 0..R-1 take
// sigmoid(preds[b, labels[b]]); blocks R..2R-1 take targets[b-R]. Each block
// computes the normalized squared distance field (field^2) of its image and
// stores it TRANSPOSED as [px][i] into the workspace for coalesced phase-B
// reads. Pred blocks also emit err = (sigmoid - target)^2, transposed.
//
// Phase B (same grid): one WAVE per pixel. Lane i holds samples 2i, 2i+1
// (float2 coalesced loads), shuffle-based inclusive scan over R=128,
// dot with err, butterfly reduce, one atomicAdd per pixel.
__global__ __launch_bounds__(256) void hd_loss_coop(
    const float* __restrict__ preds,
    const float* __restrict__ targets,
    const int* __restrict__ labels,
    float* __restrict__ distP_t,  // [784, R] field^2 of pred images (transposed)
    float* __restrict__ distT_t,  // [784, R] field^2 of target images (transposed)
    float* __restrict__ err_t,    // [784, R] (sigmoid - target)^2 (transposed)
    float* __restrict__ out)
{
    __shared__ unsigned fgrow[HH];        // fg mask bits per row (28 bits)
    __shared__ int rowd[2][HH][WW];       // min sq horiz dist to class-c pixel in row r, col x
    __shared__ int md2[NPIX];             // per-pixel min sq dist to opposite class
    __shared__ int redF[256], redB[256];  // max-reduce scratch
    __shared__ float invF, invB;
    __shared__ int s_uniform;

    const int tid = threadIdx.x;
    const int b = blockIdx.x;

    if (b == 0 && tid == 0) out[0] = 0.0f;   // phase B atomics happen after grid.sync

    if (tid < HH) fgrow[tid] = 0u;
    __syncthreads();

    const bool isPred = (b < R);
    const int rb = isPred ? b : (b - R);
    const float* src;
    const float* tgt = targets + (size_t)rb * NPIX;
    if (isPred) {
        const int lab = labels[b];
        src = preds + ((size_t)b * C + (size_t)lab) * NPIX;
    } else {
        src = tgt;
    }

    // Load pixels, compute fg mask bits; pred blocks also emit err^2 transposed.
    for (int j = tid; j < NPIX; j += 256) {
        float v = src[j];
        float s;
        if (isPred) {
            s = 1.0f / (1.0f + expf(-v));
            const float e = s - tgt[j];
            err_t[(size_t)j * R + b] = e * e;
        } else {
            s = v;
        }
        if (s > 0.5f) {
            atomicOr(&fgrow[j / WW], 1u << (j % WW));
        }
    }
    __syncthreads();

    // Build rowd[c][r][x]: min over columns kx with class(r,kx)==c of (x-kx)^2.
    for (int e = tid; e < 2 * NPIX; e += 256) {
        const int c = (e >= NPIX);
        const int rem = e - c * NPIX;
        const int r = rem / WW;
        const int x = rem - r * WW;
        const unsigned fr = fgrow[r];
        const unsigned w = c ? fr : (~fr & 0x0FFFFFFFu);
        int dv;
        if (w == 0u) {
            dv = BIGD;
        } else {
            const unsigned wl = w & ((2u << x) - 1u);  // bits 0..x
            const unsigned wr = w >> x;                // bits x..27
            const int dl = wl ? (x - (31 - __builtin_clz(wl))) : 10000;
            const int dr = wr ? __builtin_ctz(wr) : 10000;
            const int d = dl < dr ? dl : dr;
            dv = d * d;
        }
        rowd[c][r][x] = dv;
    }
    __syncthreads();

    // Per-pixel: min over 28 rows of dy^2 + rowd[opposite][r][x]; track per-class max.
    int localF = -1, localB = -1;
    for (int j = tid; j < NPIX; j += 256) {
        const int y = j / WW;
        const int x = j - y * WW;
        const int c = (fgrow[y] >> x) & 1;
        const int* rd = &rowd[c ^ 1][0][x];
        int m = 0x3FFFFFFF;
        #pragma unroll
        for (int r = 0; r < HH; ++r) {
            const int dy = y - r;
            const int cand = dy * dy + rd[r * WW];
            m = cand < m ? cand : m;
        }
        md2[j] = m;
        if (c) localF = m > localF ? m : localF;
        else   localB = m > localB ? m : localB;
    }
    redF[tid] = localF;
    redB[tid] = localB;
    __syncthreads();
    for (int s = 128; s > 0; s >>= 1) {
        if (tid < s) {
            redF[tid] = redF[tid + s] > redF[tid] ? redF[tid + s] : redF[tid];
            redB[tid] = redB[tid + s] > redB[tid] ? redB[tid + s] : redB[tid];
        }
        __syncthreads();
    }
    if (tid == 0) {
        const int mF = redF[0], mB = redB[0];
        if (mF < 0 || mB < 0) {   // uniform mask (or empty): field is identically 0
            s_uniform = 1; invF = 0.0f; invB = 0.0f;
        } else {
            s_uniform = 0;
            invF = 1.0f / (float)mF;   // field^2 = md2 / max_md2(same class)
            invB = 1.0f / (float)mB;
        }
    }
    __syncthreads();

    float* dst = isPred ? distP_t : distT_t;
    const int uni = s_uniform;
    for (int j = tid; j < NPIX; j += 256) {
        float fsq = 0.0f;
        if (!uni) {
            const int y = j / WW;
            const int x = j - y * WW;
            const int c = (fgrow[y] >> x) & 1;
            fsq = (float)md2[j] * (c ? invF : invB);
        }
        dst[(size_t)j * R + rb] = fsq;
    }

    // ---- grid-wide barrier: all transposed intermediates visible ----
    __threadfence();
    cg::grid_group grid = cg::this_grid();
    grid.sync();

    // ---- Phase B: one wave per pixel ----
    const int wv = (b << 2) + (tid >> 6);   // 256 blocks * 4 waves = 1024 >= 784
    const int lane = tid & 63;
    if (wv < NPIX) {
        const size_t o = (size_t)wv * R + 2 * lane;
        const float2 dp = *(const float2*)(distP_t + o);
        const float2 dt = *(const float2*)(distT_t + o);
        const float2 e2 = *(const float2*)(err_t + o);
        const float d0 = dp.x + dt.x;          // dist for sample 2*lane
        const float d1 = dp.y + dt.y;          // dist for sample 2*lane+1
        float s = d0 + d1;
        // inclusive scan of per-lane pair totals over 64 lanes
        #pragma unroll
        for (int off = 1; off < 64; off <<= 1) {
            const float v = __shfl_up(s, off, 64);
            if (lane >= off) s += v;
        }
        const float cum1 = s;                  // cumsum through sample 2*lane+1
        const float cum0 = s - d1;             // cumsum through sample 2*lane
        float acc = e2.x * cum0 + e2.y * cum1;
        #pragma unroll
        for (int off = 32; off > 0; off >>= 1)
            acc += __shfl_down(acc, off, 64);
        if (lane == 0)
            atomicAdd(out, acc * (1.0f / ((float)R * (float)NPIX)));
    }
}

extern "C" void kernel_launch(void* const* d_in, const int* in_sizes, int n_in,
                              void* d_out, int out_size, void* d_ws, size_t ws_size,
                              hipStream_t stream) {
    const float* preds = (const float*)d_in[0];
    const float* targets = (const float*)d_in[1];
    const int* labels = (const int*)d_in[2];
    float* out = (float*)d_out;

    float* ws = (float*)d_ws;
    float* distP_t = ws;                        // 784*R floats
    float* distT_t = ws + (size_t)R * NPIX;     // 784*R floats
    float* err_t   = ws + (size_t)2 * R * NPIX; // 784*R floats

    void* args[] = {(void*)&preds, (void*)&targets, (void*)&labels,
                    (void*)&distP_t, (void*)&distT_t, (void*)&err_t, (void*)&out};
    hipLaunchCooperativeKernel((void*)hd_loss_coop, dim3(2 * R), dim3(256),
                               args, 0, stream);
}

// Round 3
// 91.202 us; speedup vs baseline: 1.7436x; 1.7436x over previous
//
#include <hip/hip_runtime.h>

#define R 128
#define C 80
#define HH 28
#define WW 28
#define NPIX 784          // 28*28
#define BIGD (1 << 26)    // sentinel for "no opposite pixel in this row"

// One block per image (blocks 0..R-1: sigmoid(preds[b, labels[b]]); blocks
// R..2R-1: targets[b-R]). Computes the normalized squared distance field
// (field**2) and stores it TRANSPOSED as [px][i] for coalesced phase-2 scans.
// Pred blocks also compute err = (sigmoid - target)^2, stored [px][i].
// Barrier-trimmed: 5 __syncthreads (was ~12) — max-reduce is wave-shuffle based.
__global__ __launch_bounds__(256) void edt_field_kernel(
    const float* __restrict__ preds,
    const float* __restrict__ targets,
    const int* __restrict__ labels,
    float* __restrict__ distP_t,  // [784, R] field^2 of pred images (transposed)
    float* __restrict__ distT_t,  // [784, R] field^2 of target images (transposed)
    float* __restrict__ err_t,    // [784, R] (sigmoid - target)^2 (transposed)
    float* __restrict__ out)      // zeroed by block 0 (phase 2 runs after)
{
    __shared__ unsigned fgrow[HH];        // fg mask bits per row (28 bits)
    __shared__ int rowd[2][HH][WW];       // min sq horiz dist to class-c pixel in row r, col x
    __shared__ int md2[NPIX];             // per-pixel min sq dist to opposite class
    __shared__ int red4F[4], red4B[4];    // per-wave maxima
    __shared__ float invF, invB;
    __shared__ int s_uniform;

    const int tid = threadIdx.x;
    const int b = blockIdx.x;

    if (b == 0 && tid == 0) out[0] = 0.0f;   // phase 2 (stream-ordered) atomicAdds into this

    if (tid < HH) fgrow[tid] = 0u;
    __syncthreads();                               // (1)

    const bool isPred = (b < R);
    const int rb = isPred ? b : (b - R);
    const float* src;
    const float* tgt = targets + (size_t)rb * NPIX;
    if (isPred) {
        const int lab = labels[b];
        src = preds + ((size_t)b * C + (size_t)lab) * NPIX;
    } else {
        src = tgt;
    }

    // Load pixels, compute fg mask bits; pred blocks also emit err^2 transposed.
    for (int j = tid; j < NPIX; j += 256) {
        float v = src[j];
        float s;
        if (isPred) {
            s = 1.0f / (1.0f + expf(-v));
            const float e = s - tgt[j];
            err_t[(size_t)j * R + b] = e * e;
        } else {
            s = v;
        }
        if (s > 0.5f) {
            atomicOr(&fgrow[j / WW], 1u << (j % WW));
        }
    }
    __syncthreads();                               // (2)

    // Build rowd[c][r][x]: min over columns kx with class(r,kx)==c of (x-kx)^2.
    // O(1) per entry via clz/ctz on the 28-bit row mask.
    for (int e = tid; e < 2 * NPIX; e += 256) {
        const int c = (e >= NPIX);
        const int rem = e - c * NPIX;
        const int r = rem / WW;
        const int x = rem - r * WW;
        const unsigned fr = fgrow[r];
        const unsigned w = c ? fr : (~fr & 0x0FFFFFFFu);
        int dv;
        if (w == 0u) {
            dv = BIGD;
        } else {
            const unsigned wl = w & ((2u << x) - 1u);  // bits 0..x
            const unsigned wr = w >> x;                // bits x..27
            const int dl = wl ? (x - (31 - __builtin_clz(wl))) : 10000;
            const int dr = wr ? __builtin_ctz(wr) : 10000;
            const int d = dl < dr ? dl : dr;
            dv = d * d;
        }
        rowd[c][r][x] = dv;
    }
    __syncthreads();                               // (3)

    // Per-pixel: min over 28 rows of dy^2 + rowd[opposite][r][x]; track per-class max.
    int localF = -1, localB = -1;
    for (int j = tid; j < NPIX; j += 256) {
        const int y = j / WW;
        const int x = j - y * WW;
        const int c = (fgrow[y] >> x) & 1;
        const int* rd = &rowd[c ^ 1][0][x];
        int m = 0x3FFFFFFF;
        #pragma unroll
        for (int r = 0; r < HH; ++r) {
            const int dy = y - r;
            const int cand = dy * dy + rd[r * WW];
            m = cand < m ? cand : m;
        }
        md2[j] = m;
        if (c) localF = m > localF ? m : localF;
        else   localB = m > localB ? m : localB;
    }
    // wave max-reduce (no barriers), then tiny LDS combine
    #pragma unroll
    for (int off = 32; off > 0; off >>= 1) {
        const int vF = __shfl_down(localF, off, 64);
        const int vB = __shfl_down(localB, off, 64);
        localF = vF > localF ? vF : localF;
        localB = vB > localB ? vB : localB;
    }
    if ((tid & 63) == 0) { red4F[tid >> 6] = localF; red4B[tid >> 6] = localB; }
    __syncthreads();                               // (4)
    if (tid == 0) {
        int mF = red4F[0], mB = red4B[0];
        #pragma unroll
        for (int w = 1; w < 4; ++w) {
            mF = red4F[w] > mF ? red4F[w] : mF;
            mB = red4B[w] > mB ? red4B[w] : mB;
        }
        if (mF < 0 || mB < 0) {   // uniform mask (or empty): field is identically 0
            s_uniform = 1; invF = 0.0f; invB = 0.0f;
        } else {
            s_uniform = 0;
            invF = 1.0f / (float)mF;   // field^2 = md2 / max_md2(same class)
            invB = 1.0f / (float)mB;
        }
    }
    __syncthreads();                               // (5)

    float* dst = isPred ? distP_t : distT_t;
    const int uni = s_uniform;
    for (int j = tid; j < NPIX; j += 256) {
        float fsq = 0.0f;
        if (!uni) {
            const int y = j / WW;
            const int x = j - y * WW;
            const int c = (fgrow[y] >> x) & 1;
            fsq = (float)md2[j] * (c ? invF : invB);   // md2[j]: same-thread RAW, no barrier
        }
        dst[(size_t)j * R + rb] = fsq;
    }
}

// One WAVE per pixel, zero barriers. Lane i holds samples 2i, 2i+1 (float2
// coalesced loads), shuffle inclusive scan over R=128, dot with err,
// butterfly reduce, one atomicAdd per pixel. 196 blocks x 256 thr = 784 waves.
__global__ __launch_bounds__(256) void scan_reduce_kernel(
    const float* __restrict__ distP_t,
    const float* __restrict__ distT_t,
    const float* __restrict__ err_t,
    float* __restrict__ out)
{
    const int wv = (blockIdx.x << 2) + (threadIdx.x >> 6);   // pixel index
    const int lane = threadIdx.x & 63;
    const size_t o = (size_t)wv * R + 2 * lane;

    const float2 dp = *(const float2*)(distP_t + o);
    const float2 dt = *(const float2*)(distT_t + o);
    const float2 e2 = *(const float2*)(err_t + o);
    const float d0 = dp.x + dt.x;          // dist for sample 2*lane
    const float d1 = dp.y + dt.y;          // dist for sample 2*lane+1
    float s = d0 + d1;
    // inclusive scan of per-lane pair totals over 64 lanes
    #pragma unroll
    for (int off = 1; off < 64; off <<= 1) {
        const float v = __shfl_up(s, off, 64);
        if (lane >= off) s += v;
    }
    const float cum1 = s;                  // cumsum through sample 2*lane+1
    const float cum0 = s - d1;             // cumsum through sample 2*lane
    float acc = e2.x * cum0 + e2.y * cum1;
    #pragma unroll
    for (int off = 32; off > 0; off >>= 1)
        acc += __shfl_down(acc, off, 64);
    if (lane == 0)
        atomicAdd(out, acc * (1.0f / ((float)R * (float)NPIX)));
}

extern "C" void kernel_launch(void* const* d_in, const int* in_sizes, int n_in,
                              void* d_out, int out_size, void* d_ws, size_t ws_size,
                              hipStream_t stream) {
    const float* preds = (const float*)d_in[0];
    const float* targets = (const float*)d_in[1];
    const int* labels = (const int*)d_in[2];
    float* out = (float*)d_out;

    float* ws = (float*)d_ws;
    float* distP_t = ws;                        // 784*R floats
    float* distT_t = ws + (size_t)R * NPIX;     // 784*R floats
    float* err_t   = ws + (size_t)2 * R * NPIX; // 784*R floats

    hipLaunchKernelGGL(edt_field_kernel, dim3(2 * R), dim3(256), 0, stream,
                       preds, targets, labels, distP_t, distT_t, err_t, out);
    hipLaunchKernelGGL(scan_reduce_kernel, dim3(NPIX / 4), dim3(256), 0, stream,
                       distP_t, distT_t, err_t, out);
}